// Round 3
// baseline (318.246 us; speedup 1.0000x reference)
//
#include <hip/hip_runtime.h>
#include <hip/hip_bf16.h>

// ---------------------------------------------------------------------------
// TinyMNISTNet: out = relu(x @ Wq1^T + b1) @ Wq2^T + b2, ternarized weights.
// x: [65536,784] fp32; W1: [64,784]; b1:[64]; W2:[10,64]; b2:[10]; out fp32 [65536,10].
//
// R5: fused K-loop restructured to ZERO-LDS layer 1. Each lane loads its MFMA
//     A-fragment directly (8 consecutive floats of one x row: 2x f32x4),
//     converts in-register via v_cvt_pk_bf16_f32, and feeds MFMA. Deletes the
//     per-step LDS write/read round-trip and both lgkmcnt(0) drains from the
//     hot loop (previously ~60-80 exposed cycles x 25 steps). Same HBM lines
//     touched per step (16 rows x 128B). Setup stays the R4 parallel
//     atomic-free 2-dispatch pipeline; alpha1 reduction stays in the epilogue.
// ---------------------------------------------------------------------------

typedef __attribute__((ext_vector_type(4))) float f32x4;
typedef __attribute__((ext_vector_type(8))) short s16x8;
typedef __attribute__((ext_vector_type(4))) unsigned int u32x4;

#define K1 784
#define K1_PAD 800          // 25 K-steps of 32
#define NHID 64
#define NOUT 10

// round-to-nearest-even f32 -> bf16 bits (finite inputs) — epilogue use only
static __device__ __forceinline__ unsigned short f2bf_rne(float f) {
    unsigned int u = __builtin_bit_cast(unsigned int, f);
    unsigned int r = u + 0x7FFFu + ((u >> 16) & 1u);
    return (unsigned short)(r >> 16);
}

// packed f32x2 -> bf16x2 (RNE), gfx950 HW instruction (no builtin; T12/m240)
static __device__ __forceinline__ unsigned int cvt_pk_bf16(float lo, float hi) {
    unsigned int r;
    asm("v_cvt_pk_bf16_f32 %0, %1, %2" : "=v"(r) : "v"(lo), "v"(hi));
    return r;
}

// block-wide f64 sum for 256-thread blocks (4 waves); result valid in all threads
static __device__ double block_sum256(double v, double* red) {
    #pragma unroll
    for (int off = 32; off > 0; off >>= 1) v += __shfl_down(v, off, 64);
    const int w = threadIdx.x >> 6;
    const int lane = threadIdx.x & 63;
    __syncthreads();                 // protect red[] reuse across calls
    if (lane == 0) red[w] = v;
    __syncthreads();
    return red[0] + red[1] + red[2] + red[3];
}

// ---------------------------------------------------------------------------
// ws layout (see kernel_launch):
//   p1[64]   : per-block partial sum|W1|
//   psm[64]  : per-row sum of kept |W1| (written by quant kernel)
//   pcn[64]  : per-row kept count
//   p2,a2    : sum|W2| (exact), alpha2 (exact)
//   W1q      : [64][800] bf16 sign values (cols 784..799 zero)
//   W2q      : [16][64]  bf16 sign values (rows 10..15 zero)
// ---------------------------------------------------------------------------

__global__ __launch_bounds__(256) void tern_sum_kernel(
    const float* __restrict__ W1, const float* __restrict__ W2,
    double* __restrict__ p1, double* __restrict__ p2)
{
    __shared__ double red[4];
    const int gid = blockIdx.x * 256 + threadIdx.x;

    // W1: 50176 floats = 12544 f32x4; 64 blocks x 256 threads = 16384 slots
    double s = 0.0;
    if (gid < (NHID * K1) / 4) {
        f32x4 v = ((const f32x4*)W1)[gid];
        s = (double)fabsf(v[0]) + (double)fabsf(v[1])
          + (double)fabsf(v[2]) + (double)fabsf(v[3]);
    }
    s = block_sum256(s, red);
    if (threadIdx.x == 0) p1[blockIdx.x] = s;

    if (blockIdx.x == 0) {
        // W2: 640 floats = 160 f32x4
        double s2 = 0.0;
        if (threadIdx.x < (NOUT * NHID) / 4) {
            f32x4 v = ((const f32x4*)W2)[threadIdx.x];
            s2 = (double)fabsf(v[0]) + (double)fabsf(v[1])
               + (double)fabsf(v[2]) + (double)fabsf(v[3]);
        }
        s2 = block_sum256(s2, red);
        if (threadIdx.x == 0) p2[0] = s2;
    }
}

__global__ __launch_bounds__(256) void tern_quant_kernel(
    const float* __restrict__ W1, const float* __restrict__ W2,
    unsigned short* __restrict__ W1q, unsigned short* __restrict__ W2q,
    const double* __restrict__ p1, const double* __restrict__ p2,
    double* __restrict__ psm, double* __restrict__ pcn,
    double* __restrict__ a2)
{
    __shared__ double red[4];

    // reduce the 64 partials -> total sum|W1| (all blocks redundantly, L2/L3-hot)
    double v = (threadIdx.x < 64) ? p1[threadIdx.x] : 0.0;
    const double s1 = block_sum256(v, red);
    const float delta1 = (float)(0.7 * s1 / (double)(NHID * K1));

    // this block quantizes W1 row n -> padded [800] bf16 signs
    const int n = blockIdx.x;
    double sm = 0.0, cn = 0.0;
    for (int k = threadIdx.x; k < K1_PAD; k += 256) {
        unsigned short q = 0;
        if (k < K1) {
            float w = W1[n * K1 + k];
            float a = fabsf(w);
            if (a > delta1) { q = (w > 0.0f) ? 0x3F80u : 0xBF80u; sm += (double)a; cn += 1.0; }
        }
        W1q[n * K1_PAD + k] = q;
    }
    sm = block_sum256(sm, red);
    cn = block_sum256(cn, red);
    if (threadIdx.x == 0) { psm[n] = sm; pcn[n] = cn; }

    if (blockIdx.x == 0) {
        const float delta2 = (float)(0.7 * p2[0] / (double)(NOUT * NHID));
        double sm2 = 0.0, cn2 = 0.0;
        for (int i = threadIdx.x; i < 16 * NHID; i += 256) {
            int r = i >> 6;
            int k = i & 63;
            unsigned short q = 0;
            if (r < NOUT) {
                float w = W2[r * NHID + k];
                float a = fabsf(w);
                if (a > delta2) { q = (w > 0.0f) ? 0x3F80u : 0xBF80u; sm2 += (double)a; cn2 += 1.0; }
            }
            W2q[i] = q;
        }
        sm2 = block_sum256(sm2, red);
        cn2 = block_sum256(cn2, red);
        if (threadIdx.x == 0) a2[0] = sm2 / fmax(cn2, 1.0);
    }
}

// ---------------------------------------------------------------------------
// Fused 2-layer kernel. 256 threads = 4 waves; each wave: 16 batch rows x all
// 64 hidden features, then 16x10 outputs. Grid: nrows/64.
//
// Layer-1 K-loop (zero LDS): MFMA A-layout is A[m=lane&15][k=quad*8+j], so
// lane (quad,low) owns 8 CONSECUTIVE floats of row m0+low. Per K-step each
// lane loads 2x f32x4 at x[m0+low][ks*32+quad*8], converts with 4
// v_cvt_pk_bf16_f32, MFMAs. The wave touches the same 16 rows x 128B lines
// per step as the old staged scheme — identical HBM traffic, no DS ops, no
// waitcnt drains. x-chunk and W1q B-fragments register-prefetched 1 step ahead.
//
// Tail (ks=24): cols 784..799 don't exist; the kf<K1 prefetch guard zero-fills
// quads 2-3, and W1q is zero-padded there, so those MFMA lanes contribute 0.
//
// MFMA 16x16x32 bf16 layouts (m89/m91/m120-verified):
//   A[m=lane&15][k=quad*8+j], B[n=lane&15][k=quad*8+j], C/D: col=lane&15, row=quad*4+reg
// ---------------------------------------------------------------------------
__global__ __launch_bounds__(256) void fused_kernel(
    const float* __restrict__ x,
    const float* __restrict__ b1,
    const float* __restrict__ b2,
    const short* __restrict__ W1q,   // [64][800] bf16 signs
    const short* __restrict__ W2q,   // [16][64]  bf16 signs
    const double* __restrict__ psm,  // [64] per-row kept-sum partials
    const double* __restrict__ pcn,  // [64] per-row kept-count partials
    const double* __restrict__ a2,   // [1] alpha2 (exact)
    float* __restrict__ out)
{
    const int tid  = threadIdx.x;
    const int wave = tid >> 6;
    const int lane = tid & 63;
    const int low  = lane & 15;
    const int quad = lane >> 4;

    const int m0 = blockIdx.x * 64 + wave * 16;

    // per-lane A-fragment base: row m0+low, starting float quad*8
    const float* ga = x + (size_t)(m0 + low) * K1 + quad * 8;

    __shared__ __align__(16) unsigned short h_lds[4][16][72];  // layer-2 A staging

    const short* wbase = W1q + (size_t)low * K1_PAD + quad * 8;

    f32x4 acc[4];
    #pragma unroll
    for (int nt = 0; nt < 4; ++nt) acc[nt] = (f32x4){0.f, 0.f, 0.f, 0.f};

    const f32x4 zero4 = (f32x4){0.f, 0.f, 0.f, 0.f};

    // prologue: x chunk 0 (all lanes valid: cols quad*8..quad*8+7 <= 31) and
    // B fragments for ks=0
    f32x4 c0 = *(const f32x4*)(ga);
    f32x4 c1 = *(const f32x4*)(ga + 4);
    s16x8 bf[4];
    #pragma unroll
    for (int nt = 0; nt < 4; ++nt)
        bf[nt] = *(const s16x8*)(wbase + (size_t)nt * 16 * K1_PAD);

    for (int ks = 0; ks < 25; ++ks) {
        // prefetch next x chunk + next B fragments (one full iteration ahead)
        f32x4 n0 = zero4, n1 = zero4;
        s16x8 bn[4];
        if (ks < 24) {
            const short* wn = wbase + (ks + 1) * 32;
            #pragma unroll
            for (int nt = 0; nt < 4; ++nt)
                bn[nt] = *(const s16x8*)(wn + (size_t)nt * 16 * K1_PAD);
            const int kf = (ks + 1) * 32 + quad * 8;
            if (kf < K1) {               // tail chunk: quads 2-3 stay zero
                n0 = *(const f32x4*)(ga + (ks + 1) * 32);
                n1 = *(const f32x4*)(ga + (ks + 1) * 32 + 4);
            }
        }

        // convert current chunk -> A fragment (8 sequential bf16), MFMA
        u32x4 au;
        au[0] = cvt_pk_bf16(c0[0], c0[1]);
        au[1] = cvt_pk_bf16(c0[2], c0[3]);
        au[2] = cvt_pk_bf16(c1[0], c1[1]);
        au[3] = cvt_pk_bf16(c1[2], c1[3]);
        s16x8 a = __builtin_bit_cast(s16x8, au);

        #pragma unroll
        for (int nt = 0; nt < 4; ++nt)
            acc[nt] = __builtin_amdgcn_mfma_f32_16x16x32_bf16(a, bf[nt], acc[nt], 0, 0, 0);

        #pragma unroll
        for (int nt = 0; nt < 4; ++nt) bf[nt] = bn[nt];
        c0 = n0; c1 = n1;
    }

    // ---- alpha1 reduction (per-wave, redundant, L2/L3-hot: 64 doubles each) ----
    double vs = psm[lane], vc = pcn[lane];
    #pragma unroll
    for (int off = 32; off > 0; off >>= 1) {
        vs += __shfl_down(vs, off, 64);
        vc += __shfl_down(vc, off, 64);
    }
    vs = __shfl(vs, 0, 64);
    vc = __shfl(vc, 0, 64);
    const float alpha1 = (float)(vs / fmax(vc, 1.0));
    const float alpha2 = (float)a2[0];

    // ---- epilogue 1: alpha1*acc + b1, relu, bf16 -> LDS (C-layout -> A-layout) ----
    #pragma unroll
    for (int nt = 0; nt < 4; ++nt) {
        const int n = nt * 16 + low;
        const float bias = b1[n];
        #pragma unroll
        for (int r = 0; r < 4; ++r) {
            float hv = fmaxf(0.0f, fmaf(alpha1, acc[nt][r], bias));
            h_lds[wave][quad * 4 + r][n] = f2bf_rne(hv);
        }
    }
    __asm__ volatile("s_waitcnt lgkmcnt(0)" ::: "memory");

    // ---- layer 2: [16x64] x [64x16] via 2 MFMA steps ----
    s16x8 a0 = *(const s16x8*)(&h_lds[wave][low][quad * 8]);
    s16x8 a1 = *(const s16x8*)(&h_lds[wave][low][32 + quad * 8]);
    s16x8 w0 = *(const s16x8*)(W2q + low * 64 + quad * 8);
    s16x8 w1 = *(const s16x8*)(W2q + low * 64 + 32 + quad * 8);

    f32x4 acc2 = (f32x4){0.f, 0.f, 0.f, 0.f};
    acc2 = __builtin_amdgcn_mfma_f32_16x16x32_bf16(a0, w0, acc2, 0, 0, 0);
    acc2 = __builtin_amdgcn_mfma_f32_16x16x32_bf16(a1, w1, acc2, 0, 0, 0);

    // ---- epilogue 2: alpha2*acc2 + b2, store fp32 ----
    if (low < NOUT) {
        const float bias2 = b2[low];
        #pragma unroll
        for (int r = 0; r < 4; ++r) {
            const int row = m0 + quad * 4 + r;
            out[(size_t)row * NOUT + low] = fmaf(alpha2, acc2[r], bias2);
        }
    }
}

// ---------------------------------------------------------------------------
extern "C" void kernel_launch(void* const* d_in, const int* in_sizes, int n_in,
                              void* d_out, int out_size, void* d_ws, size_t ws_size,
                              hipStream_t stream) {
    const float* x  = (const float*)d_in[0];
    const float* W1 = (const float*)d_in[1];
    const float* b1 = (const float*)d_in[2];
    const float* W2 = (const float*)d_in[3];
    const float* b2 = (const float*)d_in[4];
    float* out = (float*)d_out;

    const int nrows = in_sizes[0] / K1;   // 65536

    // ws layout (all 64B-aligned):
    //   [0]      p1[64] doubles      (512B)
    //   [512]    psm[64] doubles     (512B)
    //   [1024]   pcn[64] doubles     (512B)
    //   [1536]   p2, a2 doubles      (64B block)
    //   [2048]   W1q [64*800] ushort (100KB)
    //   then     W2q [16*64] ushort
    char* base = (char*)d_ws;
    double* p1  = (double*)(base);
    double* psm = (double*)(base + 512);
    double* pcn = (double*)(base + 1024);
    double* p2  = (double*)(base + 1536);
    double* a2  = (double*)(base + 1544);
    unsigned short* W1q = (unsigned short*)(base + 2048);
    unsigned short* W2q = W1q + NHID * K1_PAD;

    tern_sum_kernel<<<64, 256, 0, stream>>>(W1, W2, p1, p2);
    tern_quant_kernel<<<64, 256, 0, stream>>>(W1, W2, W1q, W2q, p1, p2, psm, pcn, a2);

    const int nblocks = nrows / 64;       // 64 rows per block (16 per wave)
    fused_kernel<<<nblocks, 256, 0, stream>>>(x, b1, b2, (const short*)W1q,
                                              (const short*)W2q, psm, pcn, a2, out);
}